// Round 4
// baseline (118.400 us; speedup 1.0000x reference)
//
#include <hip/hip_runtime.h>

#define BATCH 4
#define VOX 1638400            // 64*160*160
#define VOX4 (VOX / 4)
#define BLOCKS_X 256
#define THREADS 256
#define NACC 17                // A, P[1..8], N[1..8]
#define NTOT (NACC * BATCH)    // 68
#define TOTAL_BLOCKS (BLOCKS_X * BATCH)   // 1024
#define FLAGS_OFF (NTOT * BLOCKS_X)       // uint words into ws
#define MAGIC 0x13579BDFu

__device__ __forceinline__ float p0_of(float d) {
    // softmax class0 of 2 classes: p0 = 1/(1+exp(x1-x0)); d = x1-x0
    float e = __expf(d);
    return __builtin_amdgcn_rcpf(1.0f + e);   // ~1ulp; threshold is 1e-2
}

// ---------------------------------------------------------------------------
// Single-pass kernel. Cross-block communication uses ONLY device-scope
// atomics (performed at the device-coherent point) — NO __threadfence():
// on multi-XCD gfx950 an agent-scope fence costs a per-block L2
// writeback/invalidate (the R2 disaster, 2.7% VALU / 200 µs).
// ws layout (uint words): [0,68*256)   partials, row p=j*BATCH+b, col bx
//                         [FLAGS_OFF, +1024) per-block completion flags
// ---------------------------------------------------------------------------
__global__ __launch_bounds__(THREADS) void blob_onepass_kernel(
    const float* __restrict__ x, const int* __restrict__ ml,
    unsigned int* __restrict__ ws, float* __restrict__ out)
{
    const int b  = blockIdx.y;
    const int bx = blockIdx.x;
    const float4* __restrict__ x0v = (const float4*)(x + (size_t)b * 2 * VOX);
    const float4* __restrict__ x1v = (const float4*)(x + (size_t)b * 2 * VOX + VOX);
    const int4*   __restrict__ mlv = (const int4*)(ml + (size_t)b * VOX);

    float accA = 0.f;
    float accP[8], accN[8];
#pragma unroll
    for (int k = 0; k < 8; ++k) { accP[k] = 0.f; accN[k] = 0.f; }

    const int stride = BLOCKS_X * THREADS;
    for (int i = bx * THREADS + threadIdx.x; i < VOX4; i += stride) {
        float4 a0 = x0v[i];
        float4 a1 = x1v[i];
        int4   m  = mlv[i];
        float p0 = p0_of(a1.x - a0.x);
        float p1 = p0_of(a1.y - a0.y);
        float p2 = p0_of(a1.z - a0.z);
        float p3 = p0_of(a1.w - a0.w);
        int orl = m.x | m.y | m.z | m.w;
        if (__ballot(orl != 0) == 0ull) {
            accA += (p0 + p1) + (p2 + p3);      // pure-background wave (~90%)
        } else {
            accA += (m.x == 0 ? p0 : 0.f) + (m.y == 0 ? p1 : 0.f) +
                    (m.z == 0 ? p2 : 0.f) + (m.w == 0 ? p3 : 0.f);
#pragma unroll
            for (int l = 1; l <= 8; ++l) {
                accP[l - 1] += (m.x == l ? p0 : 0.f) + (m.y == l ? p1 : 0.f) +
                               (m.z == l ? p2 : 0.f) + (m.w == l ? p3 : 0.f);
                accN[l - 1] += (m.x == l ? 1.f : 0.f) + (m.y == l ? 1.f : 0.f) +
                               (m.z == l ? 1.f : 0.f) + (m.w == l ? 1.f : 0.f);
            }
        }
    }

    float accs[NACC];
    accs[0] = accA;
#pragma unroll
    for (int k = 0; k < 8; ++k) { accs[1 + k] = accP[k]; accs[9 + k] = accN[k]; }

    // ---- block reduce: wave shuffle -> LDS across 4 waves ----
    __shared__ float red[4][NACC];
    const int lane = threadIdx.x & 63;
    const int wave = threadIdx.x >> 6;
#pragma unroll
    for (int j = 0; j < NACC; ++j) {
        float v = accs[j];
        for (int off = 32; off > 0; off >>= 1) v += __shfl_down(v, off, 64);
        if (lane == 0) red[wave][j] = v;
    }
    __syncthreads();

    // ---- publish: thread 0 exchanges 17 partials, folds old values so the
    // flag exch is data-dependent (HW must drain vmcnt first), then flags. ----
    if (threadIdx.x == 0) {
        unsigned fold = 0u;
#pragma unroll
        for (int j = 0; j < NACC; ++j) {
            float s = red[0][j] + red[1][j] + red[2][j] + red[3][j];
            unsigned old = __hip_atomic_exchange(
                &ws[((size_t)j * BATCH + b) * BLOCKS_X + bx], __float_as_uint(s),
                __ATOMIC_RELAXED, __HIP_MEMORY_SCOPE_AGENT);
            fold ^= old;
        }
        unsigned fv = MAGIC + (fold & 0u);   // == MAGIC, but depends on all olds
        __hip_atomic_exchange(&ws[FLAGS_OFF + (size_t)b * BLOCKS_X + bx], fv,
                              __ATOMIC_RELAXED, __HIP_MEMORY_SCOPE_AGENT);
    }

    // ---- designated finalizer: last-dispatched block spins on flags ----
    if (bx == BLOCKS_X - 1 && b == BATCH - 1) {
        for (;;) {
            bool mine = true;
            for (int f = threadIdx.x; f < TOTAL_BLOCKS; f += THREADS) {
                unsigned v = __hip_atomic_load(&ws[FLAGS_OFF + f],
                                               __ATOMIC_RELAXED, __HIP_MEMORY_SCOPE_AGENT);
                mine &= (v == MAGIC);
            }
            if (__syncthreads_and((int)mine)) break;
            __builtin_amdgcn_s_sleep(8);
        }

        __shared__ double totals[NTOT];
        for (int p = wave; p < NTOT; p += 4) {
            double s = 0.0;
#pragma unroll
            for (int i = 0; i < BLOCKS_X / 64; ++i) {
                unsigned u = __hip_atomic_load(&ws[(size_t)p * BLOCKS_X + lane + i * 64],
                                               __ATOMIC_RELAXED, __HIP_MEMORY_SCOPE_AGENT);
                s += (double)__uint_as_float(u);
            }
            for (int off = 32; off > 0; off >>= 1) s += __shfl_down(s, off, 64);
            if (lane == 0) totals[p] = s;
        }
        __syncthreads();

        if (threadIdx.x == 0) {
            const double Vd = (double)VOX;
            const double TA = 0.3, TB = 0.7;
            double sum_main = 0.0, sum_blob = 0.0;
            for (int bb = 0; bb < BATCH; ++bb) {
                double A = totals[0 * BATCH + bb];
                double P[8], N[8], SP = 0.0, SN = 0.0;
                for (int k = 0; k < 8; ++k) {
                    P[k] = totals[(1 + k) * BATCH + bb];
                    N[k] = totals[(9 + k) * BATCH + bb];
                    SP += P[k]; SN += N[k];
                }
                double n0 = Vd - SN;
                { // main, class 0 (g = background)
                    double tp = A, fp = SP, fn = n0 - A;
                    sum_main += tp / fmax(tp + TA * fp + TB * fn, 1e-8);
                }
                { // main, class 1 (g = foreground)
                    double tp = SN - SP, fp = n0 - A, fn = SP;
                    sum_main += tp / fmax(tp + TA * fp + TB * fn, 1e-8);
                }
                for (int k = 0; k < 8; ++k) {
                    double mo = SN - N[k];           // other blobs -> p=(.5,.5)
                    { // class 0: g = (L != lab)
                        double tp = A + 0.5 * mo;
                        double fp = P[k];
                        double fn = (Vd - N[k]) - tp;
                        sum_blob += tp / fmax(tp + TA * fp + TB * fn, 1e-8);
                    }
                    { // class 1: g = (L == lab)
                        double tp = N[k] - P[k];
                        double fp = (n0 - A) + 0.5 * mo;
                        double fn = P[k];
                        sum_blob += tp / fmax(tp + TA * fp + TB * fn, 1e-8);
                    }
                }
            }
            out[0] = (float)(-(sum_main / 8.0 + sum_blob / 128.0));
        }
    }
}

extern "C" void kernel_launch(void* const* d_in, const int* in_sizes, int n_in,
                              void* d_out, int out_size, void* d_ws, size_t ws_size,
                              hipStream_t stream) {
    const float* x  = (const float*)d_in[0];
    const int*   ml = (const int*)d_in[1];
    float* out      = (float*)d_out;
    unsigned int* ws = (unsigned int*)d_ws;   // 68*256 partials + 1024 flags (~72 KiB)

    dim3 grid(BLOCKS_X, BATCH);
    blob_onepass_kernel<<<grid, THREADS, 0, stream>>>(x, ml, ws, out);
}

// Round 5
// 114.673 us; speedup vs baseline: 1.0325x; 1.0325x over previous
//
#include <hip/hip_runtime.h>

#define BATCH 4
#define VOX 1638400            // 64*160*160
#define VOX4 (VOX / 4)         // 409600 float4-groups per sample
#define BX 320                 // blocks per sample
#define THREADS 256
#define ITERS 5                // 320*256*5 == 409600 exactly
#define NACC 17                // A, P[1..8], N[1..8]
#define NTOT (NACC * BATCH)    // 68

__device__ __forceinline__ float p0_of(float d) {
    // softmax class0 of 2 classes: p0 = 1/(1+exp(x1-x0)); d = x1-x0
    float e = __expf(d);
    return __builtin_amdgcn_rcpf(1.0f + e);   // ~1ulp; threshold is 1e-2
}

// ---------------------------------------------------------------------------
// Kernel 1: contiguous per-block tile, ALL 15 loads issued up front
// (register arrays, full unroll) -> ~15 KB in flight per wave, so the
// compiler can stagger vmcnt waits and the CU stays memory-pipelined.
// The R1-R4 grid-stride version exposed one load round-trip per short
// iteration -> 41 us latency-bound at 1.9 TB/s effective.
// partials layout: [(j*BATCH + b) * BX + bx], j in [0,17)
// ---------------------------------------------------------------------------
__global__ __launch_bounds__(THREADS, 4) void blob_reduce_kernel(
    const float* __restrict__ x, const int* __restrict__ ml,
    float* __restrict__ partials)
{
    const int b  = blockIdx.y;
    const int bx = blockIdx.x;
    const int t  = threadIdx.x;
    const float4* __restrict__ x0v = (const float4*)(x + (size_t)b * 2 * VOX);
    const float4* __restrict__ x1v = (const float4*)(x + (size_t)b * 2 * VOX + VOX);
    const int4*   __restrict__ mlv = (const int4*)(ml + (size_t)b * VOX);

    const int base = bx * (THREADS * ITERS) + t;

    // ---- issue all loads first (independent addresses, 15 in flight) ----
    float4 a0[ITERS], a1[ITERS];
    int4   mm[ITERS];
#pragma unroll
    for (int k = 0; k < ITERS; ++k) {
        const int i = base + k * THREADS;
        a0[k] = x0v[i];
        a1[k] = x1v[i];
        mm[k] = mlv[i];
    }

    float accA = 0.f;
    float accP[8], accN[8];
#pragma unroll
    for (int k = 0; k < 8; ++k) { accP[k] = 0.f; accN[k] = 0.f; }

    // ---- compute in load-return order ----
#pragma unroll
    for (int k = 0; k < ITERS; ++k) {
        const int4 m = mm[k];
        float p0 = p0_of(a1[k].x - a0[k].x);
        float p1 = p0_of(a1[k].y - a0[k].y);
        float p2 = p0_of(a1[k].z - a0[k].z);
        float p3 = p0_of(a1[k].w - a0[k].w);
        int orl = m.x | m.y | m.z | m.w;
        if (__ballot(orl != 0) == 0ull) {
            accA += (p0 + p1) + (p2 + p3);      // pure-background wave (~70-90%)
        } else {
            accA += (m.x == 0 ? p0 : 0.f) + (m.y == 0 ? p1 : 0.f) +
                    (m.z == 0 ? p2 : 0.f) + (m.w == 0 ? p3 : 0.f);
#pragma unroll
            for (int l = 1; l <= 8; ++l) {
                accP[l - 1] += (m.x == l ? p0 : 0.f) + (m.y == l ? p1 : 0.f) +
                               (m.z == l ? p2 : 0.f) + (m.w == l ? p3 : 0.f);
                accN[l - 1] += (m.x == l ? 1.f : 0.f) + (m.y == l ? 1.f : 0.f) +
                               (m.z == l ? 1.f : 0.f) + (m.w == l ? 1.f : 0.f);
            }
        }
    }

    float accs[NACC];
    accs[0] = accA;
#pragma unroll
    for (int k = 0; k < 8; ++k) { accs[1 + k] = accP[k]; accs[9 + k] = accN[k]; }

    // ---- block reduce: wave shuffle (64 lanes) -> LDS across 4 waves ----
    __shared__ float red[4][NACC];
    const int lane = threadIdx.x & 63;
    const int wave = threadIdx.x >> 6;
#pragma unroll
    for (int j = 0; j < NACC; ++j) {
        float v = accs[j];
        for (int off = 32; off > 0; off >>= 1) v += __shfl_down(v, off, 64);
        if (lane == 0) red[wave][j] = v;
    }
    __syncthreads();
    if (threadIdx.x < NACC) {
        float s = red[0][threadIdx.x] + red[1][threadIdx.x] +
                  red[2][threadIdx.x] + red[3][threadIdx.x];
        partials[((size_t)threadIdx.x * BATCH + b) * BX + bx] = s;
    }
}

// ---------------------------------------------------------------------------
// Kernel 2: reduce 320 partials per (j,b) in double, closed-form loss.
// ---------------------------------------------------------------------------
__global__ __launch_bounds__(256) void blob_finalize_kernel(
    const float* __restrict__ partials, float* __restrict__ out)
{
    __shared__ double totals[NTOT];   // index p = j*BATCH + b
    const int lane = threadIdx.x & 63;
    const int wave = threadIdx.x >> 6;        // 4 waves

    for (int p = wave; p < NTOT; p += 4) {
        double s = 0.0;
#pragma unroll
        for (int i = 0; i < BX / 64; ++i)
            s += (double)partials[(size_t)p * BX + lane + i * 64];
        for (int off = 32; off > 0; off >>= 1) s += __shfl_down(s, off, 64);
        if (lane == 0) totals[p] = s;
    }
    __syncthreads();

    if (threadIdx.x == 0) {
        const double Vd = (double)VOX;
        const double TA = 0.3, TB = 0.7;
        double sum_main = 0.0, sum_blob = 0.0;
        for (int bb = 0; bb < BATCH; ++bb) {
            double A = totals[0 * BATCH + bb];
            double P[8], N[8], SP = 0.0, SN = 0.0;
            for (int k = 0; k < 8; ++k) {
                P[k] = totals[(1 + k) * BATCH + bb];
                N[k] = totals[(9 + k) * BATCH + bb];
                SP += P[k]; SN += N[k];
            }
            double n0 = Vd - SN;
            { // main, class 0 (g = background)
                double tp = A, fp = SP, fn = n0 - A;
                sum_main += tp / fmax(tp + TA * fp + TB * fn, 1e-8);
            }
            { // main, class 1 (g = foreground)
                double tp = SN - SP, fp = n0 - A, fn = SP;
                sum_main += tp / fmax(tp + TA * fp + TB * fn, 1e-8);
            }
            for (int k = 0; k < 8; ++k) {
                double mo = SN - N[k];           // other-blob voxels -> p=(.5,.5)
                { // class 0: g = (L != lab)
                    double tp = A + 0.5 * mo;
                    double fp = P[k];
                    double fn = (Vd - N[k]) - tp;
                    sum_blob += tp / fmax(tp + TA * fp + TB * fn, 1e-8);
                }
                { // class 1: g = (L == lab)
                    double tp = N[k] - P[k];
                    double fp = (n0 - A) + 0.5 * mo;
                    double fn = P[k];
                    sum_blob += tp / fmax(tp + TA * fp + TB * fn, 1e-8);
                }
            }
        }
        out[0] = (float)(-(sum_main / 8.0 + sum_blob / 128.0));
    }
}

extern "C" void kernel_launch(void* const* d_in, const int* in_sizes, int n_in,
                              void* d_out, int out_size, void* d_ws, size_t ws_size,
                              hipStream_t stream) {
    const float* x  = (const float*)d_in[0];
    const int*   ml = (const int*)d_in[1];
    float* out      = (float*)d_out;
    float* partials = (float*)d_ws;   // NTOT*320 floats = 87 KiB

    dim3 grid(BX, BATCH);
    blob_reduce_kernel<<<grid, THREADS, 0, stream>>>(x, ml, partials);
    blob_finalize_kernel<<<1, 256, 0, stream>>>(partials, out);
}